// Round 7
// baseline (303.347 us; speedup 1.0000x reference)
//
#include <hip/hip_runtime.h>
#include <hip/hip_bf16.h>

// ModulatedConv2d: out = oscale[b,co] * conv2d(s[b,ci]*x, w_bf16)
// B=8, C=512, K=3, H=W=64.
// Round 7: DPP column-shift. Read only dw=0 x-fragments from LDS (4/dh);
// derive dw=+-1 fragments in-register via update_dpp row shifts (boundary
// lanes patched from neighbor frag, extreme edges zero = halo). Cuts per-wave
// LDS reads 108->84 per chunk so the LDS pipe fits under the MFMA shadow.
// Staging schedule unchanged from round 6 (counted vmcnt, 2 barriers/chunk).

#define CDIM 512
#define HW 64
#define CK 32
#define NCHUNK 16   // 512/32

typedef __attribute__((ext_vector_type(8))) short short8;
typedef __attribute__((ext_vector_type(4))) float float4v;
typedef __attribute__((ext_vector_type(4))) int int4v;

__device__ __forceinline__ short f2bf(float f) {
    unsigned u = __float_as_uint(f);
    unsigned r = (u + 0x7FFFu + ((u >> 16) & 1u)) >> 16;
    return (short)r;
}

__device__ __forceinline__ void async_ld16(const short* g, short* l) {
    __builtin_amdgcn_global_load_lds(
        (const __attribute__((address_space(1))) void*)g,
        (__attribute__((address_space(3))) void*)l, 16, 0, 0);
}

__device__ __forceinline__ void hard_sync() {
    asm volatile("s_waitcnt vmcnt(0) lgkmcnt(0)" ::: "memory");
    __builtin_amdgcn_sched_barrier(0);
    __builtin_amdgcn_s_barrier();
    __builtin_amdgcn_sched_barrier(0);
}

// update_dpp lane shift on a bf16x8 frag. CTRL: 0x100+N=row_shl:N (out[n]=in[n+? see below]),
// 0x110+N=row_shr:N. Semantics (scan-idiom anchor): row_shr:N -> out[n]=in[n-N];
// row_shl:N -> out[n]=in[n+N]. Invalid lanes take OLD (bound_ctrl=false).
template<int CTRL>
__device__ __forceinline__ short8 dppsh(short8 src, short8 oldv) {
    int4v s = __builtin_bit_cast(int4v, src);
    int4v o = __builtin_bit_cast(int4v, oldv);
    int4v r;
#pragma unroll
    for (int k = 0; k < 4; ++k)
        r[k] = __builtin_amdgcn_update_dpp(o[k], s[k], CTRL, 0xF, 0xF, false);
    return __builtin_bit_cast(short8, r);
}

// ---------------- prep kernels ----------------

__global__ void k_affine(const float* __restrict__ style, const float* __restrict__ aw,
                         const float* __restrict__ ab, float* __restrict__ s) {
    int b = blockIdx.x;
    int ci = blockIdx.y * 256 + threadIdx.x;
    const float* st = style + b * CDIM;
    const float* w = aw + ci * CDIM;
    float acc = 0.f;
    for (int k = 0; k < CDIM; ++k) acc += st[k] * w[k];
    s[b * CDIM + ci] = acc * 0.04419417382415922f + ab[ci];
}

__global__ void k_ws2(const float* __restrict__ w, float* __restrict__ ws2) {
    int i = blockIdx.x * 256 + threadIdx.x;  // 262144
    const float* p = w + i * 9;
    float a = 0.f;
#pragma unroll
    for (int t = 0; t < 9; ++t) a += p[t] * p[t];
    ws2[i] = a;
}

__global__ void k_oscale(const float* __restrict__ s, const float* __restrict__ ws2,
                         float* __restrict__ osc) {
    __shared__ float s2[CDIM];
    int b = blockIdx.x;
    int co = blockIdx.y * 256 + threadIdx.x;
    for (int i = threadIdx.x; i < CDIM; i += 256) {
        float v = s[b * CDIM + i];
        s2[i] = v * v;
    }
    __syncthreads();
    const float* r = ws2 + co * CDIM;
    float acc = 0.f;
    for (int k = 0; k < CDIM; ++k) acc += s2[k] * r[k];
    const float wg = 0.014731391274719739f;          // 1/sqrt(4608)
    const float wg2 = 2.170138888888889e-4f;         // 1/4608
    osc[b * CDIM + co] = wg * rsqrtf(wg2 * acc + 1e-8f);
}

// wgt layout: [chunk16][ct4] regions of 36864 shorts.
// Within region: [t9][mf8][slot64][j8], slot = l4*16 + l15 (lane-linear),
// value = w[co = ct*128 + mf*16 + l15][ci = chunk*32 + l4*8 + j][t]
__global__ void k_wconv(const float* __restrict__ w, short* __restrict__ wgt) {
    int idx = blockIdx.x * 256 + threadIdx.x;  // 2359296
    int j = idx & 7;
    int slotg = idx >> 3;
    int region = slotg / 4608;         // chunk*4 + ct
    int a16 = slotg - region * 4608;
    int tm = a16 >> 6;                 // t*8 + mf
    int t = tm >> 3;
    int mf = tm & 7;
    int sl = a16 & 63;
    int l4 = sl >> 4;
    int l15 = sl & 15;
    int ct = region & 3;
    int c = region >> 2;
    int co = ct * 128 + mf * 16 + l15;
    int ci = c * 32 + l4 * 8 + j;
    wgt[idx] = f2bf(w[(co * CDIM + ci) * 9 + t]);
}

// xs layout: [b8][c16][grow64] rows of 2048 shorts (LDS interior image,
// pre-swizzled): offset (lcol-1)*32 + q*8 + j holds bf16(x*s) with
// ci = c*32 + (q ^ ((lcol>>1)&3))*8 + j.
__global__ void k_xs(const float* __restrict__ x, const float* __restrict__ s,
                     short* __restrict__ xs) {
    const int bx = blockIdx.x;         // (b*16 + c)*64 + grow
    const int grow = bx & 63;
    const int t = bx >> 6;
    const int c = t & 15;
    const int b = t >> 4;
    const int q = threadIdx.x >> 6;    // 0..3
    const int lane = threadIdx.x & 63; // gcol; lcol = lane+1
    const int cig = q ^ (((lane + 1) >> 1) & 3);
    const int ci0 = c * 32 + cig * 8;
    const float* xb = x + ((b * CDIM + ci0) * HW + grow) * HW + lane;
    const float* sb = s + b * CDIM + ci0;
    short8 pk;
#pragma unroll
    for (int j = 0; j < 8; ++j)
        pk[j] = f2bf(xb[j * (HW * HW)] * sb[j]);
    *(short8*)&xs[bx * 2048 + lane * 32 + q * 8] = pk;
}

// ---------------- main conv ----------------
// grid 256 blocks x 512 threads. Block: (ct co-tile of 128, b, row-tile of 8).
__global__ __launch_bounds__(512, 1) void conv_main2(
    const short* __restrict__ xs, const short* __restrict__ zs,
    const short* __restrict__ wgt, const float* __restrict__ osc,
    float* __restrict__ out) {

    __shared__ __align__(16) short w_lds[9 * 8 * 64 * 8];    // 73728 B
    __shared__ __align__(16) short x_lds[2][10 * 66 * CK];   // 2*42240 B

    const int tid = threadIdx.x;
    const int lane = tid & 63;
    const int wid = tid >> 6;          // 0..7
    const int l15 = lane & 15;
    const int l4 = lane >> 4;

    // b == xcd; the 4 ct-blocks of one (b,rt) group share the xs slice in L2.
    const int bx = blockIdx.x;
    const int xcd = bx & 7;
    const int t7 = bx >> 3;
    const int ct = t7 & 3;
    const int ghi = t7 >> 2;           // 0..7
    const int b = xcd;
    const int r0 = ghi * 8;

    // zero halo columns (lcol 0 and 65) of both buffers, once
    for (int i = tid; i < 640; i += 512) {
        int bufi = i >= 320;
        int v = i - bufi * 320;
        int row = v >> 5;
        int w16 = v & 31;
        int colh = (w16 >= 16) ? 65 : 0;
        int q16 = w16 & 15;
        ((unsigned*)x_lds[bufi])[(row * 66 + colh) * 16 + q16] = 0u;
    }

    auto stage_w = [&](int c) {   // 9 glls/wave
        const short* src = wgt + (c * 4 + ct) * 36864;
#pragma unroll
        for (int k = 0; k < 9; ++k) {
            int off = (k * 512 + wid * 64) * 8;
            async_ld16(src + off + lane * 8, w_lds + off);
        }
    };

    auto stage_x = [&](int c, int buf) {   // 5 glls/wave, uniform (zs redirect)
        const short* xsb = xs + ((b * 16 + c) << 17);   // 64 rows * 2048
#pragma unroll
        for (int k = 0; k < 5; ++k) {
            int slot = wid * 5 + k;     // 0..39
            int row = slot >> 2;        // 0..9
            int part = slot & 3;
            int grow = r0 - 1 + row;
            const short* src = (grow >= 0 && grow < HW)
                ? xsb + grow * 2048 + part * 512
                : zs + part * 512;
            short* dst = &x_lds[buf][(row * 66 + 1) * CK] + part * 512;
            async_ld16(src + lane * 8, dst + lane * 8);
        }
    };

    float4v acc[8][4] = {};

#define TAP(T, BF)                                                              \
    { _Pragma("unroll")                                                         \
      for (int mf = 0; mf < 8; ++mf) {                                          \
          short8 af = *(const short8*)&w_lds[(((T) * 8 + mf) * 64 + lane) * 8]; \
          _Pragma("unroll")                                                     \
          for (int nf = 0; nf < 4; ++nf)                                        \
              acc[mf][nf] = __builtin_amdgcn_mfma_f32_16x16x32_bf16(            \
                  af, (BF)[nf], acc[mf][nf], 0, 0, 0);                          \
      } }

    auto compute = [&](int buf) {
        const short* xb = x_lds[buf];
        const short8 zero8 = {};
#pragma unroll
        for (int dh = 0; dh < 3; ++dh) {
            const int lrow = wid + dh;       // 0..9
            short8 R[4];
#pragma unroll
            for (int nf = 0; nf < 4; ++nf) {
                int lcol = 1 + nf * 16 + l15;
                int xq = l4 ^ ((lcol >> 1) & 3);
                R[nf] = *(const short8*)&xb[(lrow * 66 + lcol) * CK + xq * 8];
            }
            short8 S[4];
            // dw=-1: out[n]=in[n-1] (row_shr:1); lane0-of-row from prev frag's
            // lane15 (row_shl:15: out[n]=in[n+15]); nf=0 lane0 = halo = 0.
            S[0] = dppsh<0x111>(R[0], zero8);
#pragma unroll
            for (int nf = 1; nf < 4; ++nf)
                S[nf] = dppsh<0x111>(R[nf], dppsh<0x10F>(R[nf - 1], R[nf - 1]));
            TAP(dh * 3 + 1, R)       // dw=0 first (no DPP dependency)
            TAP(dh * 3 + 0, S)       // dw=-1
            // dw=+1: out[n]=in[n+1] (row_shl:1); lane15-of-row from next frag's
            // lane0 (row_shr:15: out[n]=in[n-15]); nf=3 lane15 = halo = 0.
#pragma unroll
            for (int nf = 0; nf < 3; ++nf)
                S[nf] = dppsh<0x101>(R[nf], dppsh<0x11F>(R[nf + 1], R[nf + 1]));
            S[3] = dppsh<0x101>(R[3], zero8);
            TAP(dh * 3 + 2, S)       // dw=+1
        }
    };

    // prologue: W(0), x(0)->buf0, x(1)->buf1; drain all but x(1)'s 5 glls
    stage_w(0);
    stage_x(0, 0);
    stage_x(1, 1);
    __builtin_amdgcn_sched_barrier(0);
    asm volatile("s_waitcnt vmcnt(5) lgkmcnt(0)" ::: "memory");
    __builtin_amdgcn_sched_barrier(0);
    __builtin_amdgcn_s_barrier();
    __builtin_amdgcn_sched_barrier(0);

    int cur = 0;
#pragma unroll 1
    for (int c = 0; c < NCHUNK; ++c) {
        // invariant: w_lds=W(c), x_lds[cur]=x(c) published; x(c+1) 5 glls in flight
        __builtin_amdgcn_s_setprio(1);
        compute(cur);
        __builtin_amdgcn_s_setprio(0);

        // all waves done reading w_lds and x_lds[cur]
        __builtin_amdgcn_sched_barrier(0);
        asm volatile("s_waitcnt lgkmcnt(0)" ::: "memory");
        __builtin_amdgcn_s_barrier();
        __builtin_amdgcn_sched_barrier(0);

        const int cc1 = (c + 1 < NCHUNK) ? c + 1 : NCHUNK - 1;
        const int cc2 = (c + 2 < NCHUNK) ? c + 2 : NCHUNK - 1;
        stage_w(cc1);            // 9 glls -> w_lds
        stage_x(cc2, cur);       // 5 glls -> x_lds[cur] (just-read buffer)
        __builtin_amdgcn_sched_barrier(0);

        // drain x(c+1)[5] + W(c+1)[9]; leave x(c+2)[5] in flight
        asm volatile("s_waitcnt vmcnt(5)" ::: "memory");
        __builtin_amdgcn_sched_barrier(0);
        __builtin_amdgcn_s_barrier();      // publish W(c+1), x_lds[cur^1]=x(c+1)
        __builtin_amdgcn_sched_barrier(0);
        cur ^= 1;
    }

    // epilogue: demodulate + store
    const int row_out = r0 + wid;
#pragma unroll
    for (int mf = 0; mf < 8; ++mf) {
        float4v ov = *(const float4v*)&osc[b * CDIM + ct * 128 + mf * 16 + l4 * 4];
#pragma unroll
        for (int j = 0; j < 4; ++j) {
            int co = ct * 128 + mf * 16 + l4 * 4 + j;
            float* po = out + ((b * CDIM + co) * HW + row_out) * HW;
#pragma unroll
            for (int nf = 0; nf < 4; ++nf)
                po[nf * 16 + l15] = acc[mf][nf][j] * ov[j];
        }
    }
#undef TAP
}

// ---------------- fallback conv (round-4 proven, reg-staged x) ----------------
__global__ __launch_bounds__(512, 1) void conv_main_fb(
    const float* __restrict__ x, const float* __restrict__ s,
    const short* __restrict__ wgt, const float* __restrict__ osc,
    float* __restrict__ out) {

    __shared__ __align__(16) short w_lds[9 * 8 * 64 * 8];
    __shared__ __align__(16) short x_lds[2][10 * 66 * CK];

    const int tid = threadIdx.x;
    const int lane = tid & 63;
    const int wid = tid >> 6;
    const int l15 = lane & 15;
    const int l4 = lane >> 4;

    const int bx = blockIdx.x;
    const int xcd = bx & 7;
    const int t7 = bx >> 3;
    const int ct = t7 & 3;
    const int ghi = t7 >> 2;
    const int b = xcd;
    const int r0 = ghi * 8;

    const int cig = tid & 3;
    const int col = (tid >> 2) & 63;
    const int rowhalf = tid >> 8;

    for (int i = tid; i < 640; i += 512) {
        int bufi = i >= 320;
        int v = i - bufi * 320;
        int row = v >> 5;
        int w16 = v & 31;
        int colh = (w16 >= 16) ? 65 : 0;
        int q16 = w16 & 15;
        ((unsigned*)x_lds[bufi])[(row * 66 + colh) * 16 + q16] = 0u;
    }

    float rx[40];
    float4v sva, svb;

    auto stage_w = [&](int c) {
        const short* src = wgt + (c * 4 + ct) * 36864;
#pragma unroll
        for (int k = 0; k < 9; ++k) {
            int off = (k * 512 + wid * 64) * 8;
            async_ld16(src + off + lane * 8, w_lds + off);
        }
    };

    auto stage_x_load = [&](int c) {
        const float4v* sp = (const float4v*)&s[b * CDIM + c * 32 + cig * 8];
        sva = sp[0]; svb = sp[1];
#pragma unroll
        for (int i = 0; i < 5; ++i) {
            int row = 2 * i + rowhalf;
            int grow = r0 - 1 + row;
            bool ok = (grow >= 0) && (grow < HW);
            const float* base = x + ((b * CDIM + c * 32 + cig * 8) * HW + (ok ? grow : 0)) * HW + col;
#pragma unroll
            for (int j = 0; j < 8; ++j) {
                float v = base[j * (HW * HW)];
                rx[i * 8 + j] = ok ? v : 0.0f;
            }
        }
    };

    auto stage_x_write = [&](int buf) {
        int lcol = col + 1;
        int q = cig ^ ((lcol >> 1) & 3);
#pragma unroll
        for (int i = 0; i < 5; ++i) {
            int row = 2 * i + rowhalf;
            short8 pk;
#pragma unroll
            for (int j = 0; j < 8; ++j) {
                float sj = (j < 4) ? sva[j] : svb[j - 4];
                pk[j] = f2bf(rx[i * 8 + j] * sj);
            }
            *(short8*)&x_lds[buf][(row * 66 + lcol) * CK + q * 8] = pk;
        }
    };

    float4v acc[8][4] = {};

    auto compute = [&](int buf) {
        const short* xb = x_lds[buf];
#pragma unroll
        for (int t = 0; t < 9; ++t) {
            int dh = t / 3 - 1;
            int dw = t % 3 - 1;
            int lrow = wid + dh + 1;
            short8 bfr[4];
#pragma unroll
            for (int nf = 0; nf < 4; ++nf) {
                int lcol = 1 + nf * 16 + l15 + dw;
                int xq = l4 ^ ((lcol >> 1) & 3);
                bfr[nf] = *(const short8*)&xb[(lrow * 66 + lcol) * CK + xq * 8];
            }
#pragma unroll
            for (int mf = 0; mf < 8; ++mf) {
                short8 af = *(const short8*)&w_lds[((t * 8 + mf) * 64 + lane) * 8];
#pragma unroll
                for (int nf = 0; nf < 4; ++nf)
                    acc[mf][nf] = __builtin_amdgcn_mfma_f32_16x16x32_bf16(
                        af, bfr[nf], acc[mf][nf], 0, 0, 0);
            }
        }
    };

    stage_w(0);
    stage_x_load(0);
    stage_x_write(0);
    hard_sync();

    int cur = 0;
#pragma unroll 1
    for (int c = 0; c < NCHUNK; ++c) {
        if (c + 1 < NCHUNK) stage_x_load(c + 1);
        compute(cur);
        if (c + 1 < NCHUNK) {
            hard_sync();
            stage_w(c + 1);
            stage_x_write(cur ^ 1);
            hard_sync();
            cur ^= 1;
        }
    }

    const int row_out = r0 + wid;
#pragma unroll
    for (int mf = 0; mf < 8; ++mf) {
        float4v ov = *(const float4v*)&osc[b * CDIM + ct * 128 + mf * 16 + l4 * 4];
#pragma unroll
        for (int j = 0; j < 4; ++j) {
            int co = ct * 128 + mf * 16 + l4 * 4 + j;
            float* po = out + ((b * CDIM + co) * HW + row_out) * HW;
#pragma unroll
            for (int nf = 0; nf < 4; ++nf)
                po[nf * 16 + l15] = acc[mf][nf][j] * ov[j];
        }
    }
}

// ---------------- launcher ----------------

extern "C" void kernel_launch(void* const* d_in, const int* in_sizes, int n_in,
                              void* d_out, int out_size, void* d_ws, size_t ws_size,
                              hipStream_t stream) {
    const float* x     = (const float*)d_in[0];   // 8*512*64*64
    const float* style = (const float*)d_in[1];   // 8*512
    const float* w     = (const float*)d_in[2];   // 512*512*9
    const float* aw    = (const float*)d_in[3];   // 512*512
    const float* ab    = (const float*)d_in[4];   // 512
    float* out = (float*)d_out;

    char* wsb = (char*)d_ws;
    float* s_buf = (float*)(wsb);                 // 16384 B
    float* ws2   = (float*)(wsb + 16384);         // 1048576 B
    float* osc   = (float*)(wsb + 1064960);       // 16384 B
    short* wgt   = (short*)(wsb + 1081344);       // 4718592 B
    short* zs    = (short*)(wsb + 5799936);       // 4096 B (zero page)
    short* xs    = (short*)(wsb + 5804032);       // 33554432 B
    const size_t need = 5804032ull + 33554432ull;

    k_affine<<<dim3(8, 2), 256, 0, stream>>>(style, aw, ab, s_buf);
    k_ws2<<<1024, 256, 0, stream>>>(w, ws2);
    k_wconv<<<9216, 256, 0, stream>>>(w, wgt);
    k_oscale<<<dim3(8, 2), 256, 0, stream>>>(s_buf, ws2, osc);

    if (ws_size >= need) {
        hipMemsetAsync(zs, 0, 4096, stream);
        k_xs<<<8192, 256, 0, stream>>>(x, s_buf, xs);
        conv_main2<<<256, 512, 0, stream>>>(xs, zs, wgt, osc, out);
    } else {
        conv_main_fb<<<256, 512, 0, stream>>>(x, s_buf, wgt, osc, out);
    }
}

// Round 8
// 180.260 us; speedup vs baseline: 1.6828x; 1.6828x over previous
//
#include <hip/hip_runtime.h>
#include <hip/hip_bf16.h>

// ModulatedConv2d: out = oscale[b,co] * conv2d(s[b,ci]*x, w_bf16)
// B=8, C=512, K=3, H=W=64.
// Round 8: revert DPP (spilled). 16-wave blocks (1024 thr) -> 4 waves/SIMD so
// ds_read->MFMA chains overlap across waves (m114 implicit-TLP). Wave tile
// 64co x 64px, acc[4][4]=64 regs (fits 128-VGPR budget). Uniform staging
// counts (5 W + 3 x units/wave, benign duplicates) keep counted vmcnt exact.
// Wave-parallel affine/oscale prep.

#define CDIM 512
#define HW 64
#define CK 32
#define NCHUNK 16   // 512/32

typedef __attribute__((ext_vector_type(8))) short short8;
typedef __attribute__((ext_vector_type(4))) float float4v;

__device__ __forceinline__ short f2bf(float f) {
    unsigned u = __float_as_uint(f);
    unsigned r = (u + 0x7FFFu + ((u >> 16) & 1u)) >> 16;
    return (short)r;
}

__device__ __forceinline__ void async_ld16(const short* g, short* l) {
    __builtin_amdgcn_global_load_lds(
        (const __attribute__((address_space(1))) void*)g,
        (__attribute__((address_space(3))) void*)l, 16, 0, 0);
}

__device__ __forceinline__ void hard_sync() {
    asm volatile("s_waitcnt vmcnt(0) lgkmcnt(0)" ::: "memory");
    __builtin_amdgcn_sched_barrier(0);
    __builtin_amdgcn_s_barrier();
    __builtin_amdgcn_sched_barrier(0);
}

// ---------------- prep kernels ----------------

// one wave per output: s[b][ci] = style[b,:].aw[ci,:]*g + ab[ci]
__global__ void k_affine(const float* __restrict__ style, const float* __restrict__ aw,
                         const float* __restrict__ ab, float* __restrict__ s) {
    int gid = blockIdx.x * 4 + (threadIdx.x >> 6);   // 0..4095
    int lane = threadIdx.x & 63;
    int b = gid >> 9, ci = gid & 511;
    const float4v* st = (const float4v*)(style + b * CDIM);
    const float4v* wp = (const float4v*)(aw + ci * CDIM);
    float acc = 0.f;
#pragma unroll
    for (int k = 0; k < 2; ++k) {
        float4v a = st[lane * 2 + k], w = wp[lane * 2 + k];
        acc += a[0] * w[0] + a[1] * w[1] + a[2] * w[2] + a[3] * w[3];
    }
#pragma unroll
    for (int off = 32; off; off >>= 1) acc += __shfl_down(acc, off);
    if (lane == 0) s[gid] = acc * 0.04419417382415922f + ab[ci];
}

__global__ void k_ws2(const float* __restrict__ w, float* __restrict__ ws2) {
    int i = blockIdx.x * 256 + threadIdx.x;  // 262144
    const float* p = w + i * 9;
    float a = 0.f;
#pragma unroll
    for (int t = 0; t < 9; ++t) a += p[t] * p[t];
    ws2[i] = a;
}

// one wave per (b,co): oscale = wg*rsqrt(wg^2*sum_ci s^2*ws2 + 1e-8)
__global__ void k_oscale(const float* __restrict__ s, const float* __restrict__ ws2,
                         float* __restrict__ osc) {
    int gid = blockIdx.x * 4 + (threadIdx.x >> 6);   // 0..4095
    int lane = threadIdx.x & 63;
    int b = gid >> 9, co = gid & 511;
    const float4v* sp = (const float4v*)(s + b * CDIM);
    const float4v* rp = (const float4v*)(ws2 + co * CDIM);
    float acc = 0.f;
#pragma unroll
    for (int k = 0; k < 2; ++k) {
        float4v a = sp[lane * 2 + k], r = rp[lane * 2 + k];
        acc += a[0] * a[0] * r[0] + a[1] * a[1] * r[1]
             + a[2] * a[2] * r[2] + a[3] * a[3] * r[3];
    }
#pragma unroll
    for (int off = 32; off; off >>= 1) acc += __shfl_down(acc, off);
    const float wg = 0.014731391274719739f;          // 1/sqrt(4608)
    const float wg2 = 2.170138888888889e-4f;         // 1/4608
    if (lane == 0) osc[gid] = wg * rsqrtf(wg2 * acc + 1e-8f);
}

// wgt layout: [chunk16][ct4] regions of 36864 shorts.
// Within region: [t9][mf8][slot64][j8], slot = l4*16 + l15 (lane-linear),
// value = w[co = ct*128 + mf*16 + l15][ci = chunk*32 + l4*8 + j][t]
__global__ void k_wconv(const float* __restrict__ w, short* __restrict__ wgt) {
    int idx = blockIdx.x * 256 + threadIdx.x;  // 2359296
    int j = idx & 7;
    int slotg = idx >> 3;
    int region = slotg / 4608;         // chunk*4 + ct
    int a16 = slotg - region * 4608;
    int tm = a16 >> 6;                 // t*8 + mf
    int t = tm >> 3;
    int mf = tm & 7;
    int sl = a16 & 63;
    int l4 = sl >> 4;
    int l15 = sl & 15;
    int ct = region & 3;
    int c = region >> 2;
    int co = ct * 128 + mf * 16 + l15;
    int ci = c * 32 + l4 * 8 + j;
    wgt[idx] = f2bf(w[(co * CDIM + ci) * 9 + t]);
}

// xs layout: [b8][c16][grow64] rows of 2048 shorts (LDS interior image,
// pre-swizzled): offset (lcol-1)*32 + q*8 + j holds bf16(x*s) with
// ci = c*32 + (q ^ ((lcol>>1)&3))*8 + j.
__global__ void k_xs(const float* __restrict__ x, const float* __restrict__ s,
                     short* __restrict__ xs) {
    const int bx = blockIdx.x;         // (b*16 + c)*64 + grow
    const int grow = bx & 63;
    const int t = bx >> 6;
    const int c = t & 15;
    const int b = t >> 4;
    const int q = threadIdx.x >> 6;    // 0..3
    const int lane = threadIdx.x & 63; // gcol; lcol = lane+1
    const int cig = q ^ (((lane + 1) >> 1) & 3);
    const int ci0 = c * 32 + cig * 8;
    const float* xb = x + ((b * CDIM + ci0) * HW + grow) * HW + lane;
    const float* sb = s + b * CDIM + ci0;
    short8 pk;
#pragma unroll
    for (int j = 0; j < 8; ++j)
        pk[j] = f2bf(xb[j * (HW * HW)] * sb[j]);
    *(short8*)&xs[bx * 2048 + lane * 32 + q * 8] = pk;
}

// ---------------- main conv ----------------
// grid 256 blocks x 1024 threads (16 waves = 4/SIMD).
// Block: (ct co-tile of 128, b, row-tile of 8). Wave: 64co (wm) x 1 row (wr).
__global__ __launch_bounds__(1024, 1) void conv_main2(
    const short* __restrict__ xs, const short* __restrict__ zs,
    const short* __restrict__ wgt, const float* __restrict__ osc,
    float* __restrict__ out) {

    __shared__ __align__(16) short w_lds[9 * 8 * 64 * 8];    // 73728 B
    __shared__ __align__(16) short x_lds[2][10 * 66 * CK];   // 2*42240 B

    const int tid = threadIdx.x;
    const int lane = tid & 63;
    const int wid = tid >> 6;          // 0..15
    const int wr = wid >> 1;           // 0..7 = output row within tile
    const int wm = wid & 1;            // co half (0:co 0..63, 1:co 64..127)
    const int l15 = lane & 15;
    const int l4 = lane >> 4;

    // b == xcd; the 4 ct-blocks of one (b,rt) group share the xs slice in L2.
    const int bx = blockIdx.x;
    const int xcd = bx & 7;
    const int t7 = bx >> 3;
    const int ct = t7 & 3;
    const int ghi = t7 >> 2;           // 0..7
    const int b = xcd;
    const int r0 = ghi * 8;

    // zero halo columns (lcol 0 and 65) of both buffers, once
    if (tid < 640) {
        int bufi = tid >= 320;
        int v = tid - bufi * 320;
        int row = v >> 5;
        int w16 = v & 31;
        int colh = (w16 >= 16) ? 65 : 0;
        int q16 = w16 & 15;
        ((unsigned*)x_lds[bufi])[(row * 66 + colh) * 16 + q16] = 0u;
    }

    auto stage_w = [&](int c) {   // 5 uniform 16B-units/thread (512 dup, benign)
        const short* src = wgt + (c * 4 + ct) * 36864;
#pragma unroll
        for (int k = 0; k < 5; ++k) {
            int u = tid + 1024 * k;        // 0..5119; 4608 units real
            if (u >= 4608) u -= 4608;      // wave-uniform wrap (4608 = 72*64)
            async_ld16(src + u * 8, w_lds + u * 8);
        }
    };

    auto stage_x = [&](int c, int buf) {   // 3 uniform 1KB wave-units (8 dup)
        const short* xsb = xs + ((b * 16 + c) << 17);   // 64 rows * 2048
#pragma unroll
        for (int k = 0; k < 3; ++k) {
            int u = wid + 16 * k;          // 0..47; 40 real
            if (u >= 40) u -= 40;
            int row = u >> 2;              // 0..9
            int part = u & 3;
            int grow = r0 - 1 + row;
            const short* src = (grow >= 0 && grow < HW)
                ? xsb + grow * 2048 + part * 512
                : zs + part * 512;
            short* dst = &x_lds[buf][(row * 66 + 1) * CK] + part * 512;
            async_ld16(src + lane * 8, dst + lane * 8);
        }
    };

    float4v acc[4][4] = {};

    auto compute = [&](int buf) {
        const short* xb = x_lds[buf];
#pragma unroll
        for (int t = 0; t < 9; ++t) {
            int dh = t / 3 - 1;
            int dw = t % 3 - 1;
            int lrow = wr + dh + 1;    // 0..9
            short8 bfr[4];
#pragma unroll
            for (int nf = 0; nf < 4; ++nf) {
                int lcol = 1 + nf * 16 + l15 + dw;
                int xq = l4 ^ ((lcol >> 1) & 3);
                bfr[nf] = *(const short8*)&xb[(lrow * 66 + lcol) * CK + xq * 8];
            }
#pragma unroll
            for (int mf = 0; mf < 4; ++mf) {
                short8 af = *(const short8*)&w_lds[((t * 8 + wm * 4 + mf) * 64 + lane) * 8];
#pragma unroll
                for (int nf = 0; nf < 4; ++nf)
                    acc[mf][nf] = __builtin_amdgcn_mfma_f32_16x16x32_bf16(
                        af, bfr[nf], acc[mf][nf], 0, 0, 0);
            }
        }
    };

    // prologue: W(0), x(0)->buf0, x(1)->buf1; drain all but x(1)'s 3 glls
    stage_w(0);
    stage_x(0, 0);
    stage_x(1, 1);
    __builtin_amdgcn_sched_barrier(0);
    asm volatile("s_waitcnt vmcnt(3) lgkmcnt(0)" ::: "memory");
    __builtin_amdgcn_sched_barrier(0);
    __builtin_amdgcn_s_barrier();
    __builtin_amdgcn_sched_barrier(0);

    int cur = 0;
#pragma unroll 1
    for (int c = 0; c < NCHUNK; ++c) {
        // invariant: w_lds=W(c), x_lds[cur]=x(c) published; x(c+1) 3 glls in flight
        __builtin_amdgcn_s_setprio(1);
        compute(cur);
        __builtin_amdgcn_s_setprio(0);

        // all waves done reading w_lds and x_lds[cur]
        __builtin_amdgcn_sched_barrier(0);
        asm volatile("s_waitcnt lgkmcnt(0)" ::: "memory");
        __builtin_amdgcn_s_barrier();
        __builtin_amdgcn_sched_barrier(0);

        const int cc1 = (c + 1 < NCHUNK) ? c + 1 : NCHUNK - 1;
        const int cc2 = (c + 2 < NCHUNK) ? c + 2 : NCHUNK - 1;
        stage_w(cc1);            // 5 glls -> w_lds
        stage_x(cc2, cur);       // 3 glls -> x_lds[cur] (just-read buffer)
        __builtin_amdgcn_sched_barrier(0);

        // drain x(c+1)[3] + W(c+1)[5]; leave x(c+2)[3] in flight
        asm volatile("s_waitcnt vmcnt(3)" ::: "memory");
        __builtin_amdgcn_sched_barrier(0);
        __builtin_amdgcn_s_barrier();      // publish W(c+1), x_lds[cur^1]=x(c+1)
        __builtin_amdgcn_sched_barrier(0);
        cur ^= 1;
    }

    // safety: drain the last in-flight glls before LDS lifetime ends
    asm volatile("s_waitcnt vmcnt(0)" ::: "memory");

    // epilogue: demodulate + store
    const int row_out = r0 + wr;
#pragma unroll
    for (int mf = 0; mf < 4; ++mf) {
        float4v ov = *(const float4v*)&osc[b * CDIM + ct * 128 + (wm * 4 + mf) * 16 + l4 * 4];
#pragma unroll
        for (int j = 0; j < 4; ++j) {
            int co = ct * 128 + (wm * 4 + mf) * 16 + l4 * 4 + j;
            float* po = out + ((b * CDIM + co) * HW + row_out) * HW;
#pragma unroll
            for (int nf = 0; nf < 4; ++nf)
                po[nf * 16 + l15] = acc[mf][nf][j] * ov[j];
        }
    }
}

// ---------------- fallback conv (round-4 proven, reg-staged x) ----------------
__global__ __launch_bounds__(512, 1) void conv_main_fb(
    const float* __restrict__ x, const float* __restrict__ s,
    const short* __restrict__ wgt, const float* __restrict__ osc,
    float* __restrict__ out) {

    __shared__ __align__(16) short w_lds[9 * 8 * 64 * 8];
    __shared__ __align__(16) short x_lds[2][10 * 66 * CK];

    const int tid = threadIdx.x;
    const int lane = tid & 63;
    const int wid = tid >> 6;
    const int l15 = lane & 15;
    const int l4 = lane >> 4;

    const int bx = blockIdx.x;
    const int xcd = bx & 7;
    const int t7 = bx >> 3;
    const int ct = t7 & 3;
    const int ghi = t7 >> 2;
    const int b = xcd;
    const int r0 = ghi * 8;

    const int cig = tid & 3;
    const int col = (tid >> 2) & 63;
    const int rowhalf = tid >> 8;

    for (int i = tid; i < 640; i += 512) {
        int bufi = i >= 320;
        int v = i - bufi * 320;
        int row = v >> 5;
        int w16 = v & 31;
        int colh = (w16 >= 16) ? 65 : 0;
        int q16 = w16 & 15;
        ((unsigned*)x_lds[bufi])[(row * 66 + colh) * 16 + q16] = 0u;
    }

    float rx[40];
    float4v sva, svb;

    auto stage_w = [&](int c) {
        const short* src = wgt + (c * 4 + ct) * 36864;
#pragma unroll
        for (int k = 0; k < 9; ++k) {
            int off = (k * 512 + wid * 64) * 8;
            async_ld16(src + off + lane * 8, w_lds + off);
        }
    };

    auto stage_x_load = [&](int c) {
        const float4v* sp = (const float4v*)&s[b * CDIM + c * 32 + cig * 8];
        sva = sp[0]; svb = sp[1];
#pragma unroll
        for (int i = 0; i < 5; ++i) {
            int row = 2 * i + rowhalf;
            int grow = r0 - 1 + row;
            bool ok = (grow >= 0) && (grow < HW);
            const float* base = x + ((b * CDIM + c * 32 + cig * 8) * HW + (ok ? grow : 0)) * HW + col;
#pragma unroll
            for (int j = 0; j < 8; ++j) {
                float v = base[j * (HW * HW)];
                rx[i * 8 + j] = ok ? v : 0.0f;
            }
        }
    };

    auto stage_x_write = [&](int buf) {
        int lcol = col + 1;
        int q = cig ^ ((lcol >> 1) & 3);
#pragma unroll
        for (int i = 0; i < 5; ++i) {
            int row = 2 * i + rowhalf;
            short8 pk;
#pragma unroll
            for (int j = 0; j < 8; ++j) {
                float sj = (j < 4) ? sva[j] : svb[j - 4];
                pk[j] = f2bf(rx[i * 8 + j] * sj);
            }
            *(short8*)&x_lds[buf][(row * 66 + lcol) * CK + q * 8] = pk;
        }
    };

    float4v acc[8][4] = {};

    auto compute = [&](int buf) {
        const short* xb = x_lds[buf];
#pragma unroll
        for (int t = 0; t < 9; ++t) {
            int dh = t / 3 - 1;
            int dw = t % 3 - 1;
            int lrow = wid + dh + 1;
            short8 bfr[4];
#pragma unroll
            for (int nf = 0; nf < 4; ++nf) {
                int lcol = 1 + nf * 16 + l15 + dw;
                int xq = l4 ^ ((lcol >> 1) & 3);
                bfr[nf] = *(const short8*)&xb[(lrow * 66 + lcol) * CK + xq * 8];
            }
#pragma unroll
            for (int mf = 0; mf < 8; ++mf) {
                short8 af = *(const short8*)&w_lds[((t * 8 + mf) * 64 + lane) * 8];
#pragma unroll
                for (int nf = 0; nf < 4; ++nf)
                    acc[mf][nf] = __builtin_amdgcn_mfma_f32_16x16x32_bf16(
                        af, bfr[nf], acc[mf][nf], 0, 0, 0);
            }
        }
    };

    stage_w(0);
    stage_x_load(0);
    stage_x_write(0);
    hard_sync();

    int cur = 0;
#pragma unroll 1
    for (int c = 0; c < NCHUNK; ++c) {
        if (c + 1 < NCHUNK) stage_x_load(c + 1);
        compute(cur);
        if (c + 1 < NCHUNK) {
            hard_sync();
            stage_w(c + 1);
            stage_x_write(cur ^ 1);
            hard_sync();
            cur ^= 1;
        }
    }

    const int row_out = r0 + wid;
#pragma unroll
    for (int mf = 0; mf < 8; ++mf) {
        float4v ov = *(const float4v*)&osc[b * CDIM + ct * 128 + mf * 16 + l4 * 4];
#pragma unroll
        for (int j = 0; j < 4; ++j) {
            int co = ct * 128 + mf * 16 + l4 * 4 + j;
            float* po = out + ((b * CDIM + co) * HW + row_out) * HW;
#pragma unroll
            for (int nf = 0; nf < 4; ++nf)
                po[nf * 16 + l15] = acc[mf][nf][j] * ov[j];
        }
    }
}

// ---------------- launcher ----------------

extern "C" void kernel_launch(void* const* d_in, const int* in_sizes, int n_in,
                              void* d_out, int out_size, void* d_ws, size_t ws_size,
                              hipStream_t stream) {
    const float* x     = (const float*)d_in[0];   // 8*512*64*64
    const float* style = (const float*)d_in[1];   // 8*512
    const float* w     = (const float*)d_in[2];   // 512*512*9
    const float* aw    = (const float*)d_in[3];   // 512*512
    const float* ab    = (const float*)d_in[4];   // 512
    float* out = (float*)d_out;

    char* wsb = (char*)d_ws;
    float* s_buf = (float*)(wsb);                 // 16384 B
    float* ws2   = (float*)(wsb + 16384);         // 1048576 B
    float* osc   = (float*)(wsb + 1064960);       // 16384 B
    short* wgt   = (short*)(wsb + 1081344);       // 4718592 B
    short* zs    = (short*)(wsb + 5799936);       // 4096 B (zero page)
    short* xs    = (short*)(wsb + 5804032);       // 33554432 B
    const size_t need = 5804032ull + 33554432ull;

    k_affine<<<1024, 256, 0, stream>>>(style, aw, ab, s_buf);
    k_ws2<<<1024, 256, 0, stream>>>(w, ws2);
    k_wconv<<<9216, 256, 0, stream>>>(w, wgt);
    k_oscale<<<1024, 256, 0, stream>>>(s_buf, ws2, osc);

    if (ws_size >= need) {
        hipMemsetAsync(zs, 0, 4096, stream);
        k_xs<<<8192, 256, 0, stream>>>(x, s_buf, xs);
        conv_main2<<<256, 1024, 0, stream>>>(xs, zs, wgt, osc, out);
    } else {
        conv_main_fb<<<256, 512, 0, stream>>>(x, s_buf, wgt, osc, out);
    }
}

// Round 9
// 157.458 us; speedup vs baseline: 1.9265x; 1.1448x over previous
//
#include <hip/hip_runtime.h>
#include <hip/hip_bf16.h>

// ModulatedConv2d: out = oscale[b,co] * conv2d(s[b,ci]*x, w_bf16)
// B=8, C=512, K=3, H=W=64.
// Round 9: B operand bypasses LDS. xs precomputed in B-frag-ready padded rows
// ([b][c][grow] x 66 px-cols x 32 ci, zero halos); conv loads B-frags straight
// from L2 into VGPRs (lane-affine voffset, wave-uniform tap offsets). LDS holds
// only W, double-buffered (2x73.7KB); 9 W-glls issued after tap0, land under
// the chunk's MFMAs; one barrier + vmcnt(0) per chunk. LDS reads/wave/chunk
// 108 -> 72 (A only): LDS pipe 10.4k -> 6.9k cyc vs MFMA 11.2k.

#define CDIM 512
#define HW 64
#define NCHUNK 16   // 512/32
#define XROW 2112   // shorts per xs row: 66 px-cols * 32 ci

typedef __attribute__((ext_vector_type(8))) short short8;
typedef __attribute__((ext_vector_type(4))) float float4v;

__device__ __forceinline__ short f2bf(float f) {
    unsigned u = __float_as_uint(f);
    unsigned r = (u + 0x7FFFu + ((u >> 16) & 1u)) >> 16;
    return (short)r;
}

__device__ __forceinline__ void async_ld16(const short* g, short* l) {
    __builtin_amdgcn_global_load_lds(
        (const __attribute__((address_space(1))) void*)g,
        (__attribute__((address_space(3))) void*)l, 16, 0, 0);
}

__device__ __forceinline__ void hard_sync() {
    asm volatile("s_waitcnt vmcnt(0) lgkmcnt(0)" ::: "memory");
    __builtin_amdgcn_sched_barrier(0);
    __builtin_amdgcn_s_barrier();
    __builtin_amdgcn_sched_barrier(0);
}

// ---------------- prep kernels ----------------

// one wave per output: s[b][ci] = style[b,:].aw[ci,:]*g + ab[ci]
__global__ void k_affine(const float* __restrict__ style, const float* __restrict__ aw,
                         const float* __restrict__ ab, float* __restrict__ s) {
    int gid = blockIdx.x * 4 + (threadIdx.x >> 6);   // 0..4095
    int lane = threadIdx.x & 63;
    int b = gid >> 9, ci = gid & 511;
    const float4v* st = (const float4v*)(style + b * CDIM);
    const float4v* wp = (const float4v*)(aw + ci * CDIM);
    float acc = 0.f;
#pragma unroll
    for (int k = 0; k < 2; ++k) {
        float4v a = st[lane * 2 + k], w = wp[lane * 2 + k];
        acc += a[0] * w[0] + a[1] * w[1] + a[2] * w[2] + a[3] * w[3];
    }
#pragma unroll
    for (int off = 32; off; off >>= 1) acc += __shfl_down(acc, off);
    if (lane == 0) s[gid] = acc * 0.04419417382415922f + ab[ci];
}

__global__ void k_ws2(const float* __restrict__ w, float* __restrict__ ws2) {
    int i = blockIdx.x * 256 + threadIdx.x;  // 262144
    const float* p = w + i * 9;
    float a = 0.f;
#pragma unroll
    for (int t = 0; t < 9; ++t) a += p[t] * p[t];
    ws2[i] = a;
}

// one wave per (b,co): oscale = wg*rsqrt(wg^2*sum_ci s^2*ws2 + 1e-8)
__global__ void k_oscale(const float* __restrict__ s, const float* __restrict__ ws2,
                         float* __restrict__ osc) {
    int gid = blockIdx.x * 4 + (threadIdx.x >> 6);   // 0..4095
    int lane = threadIdx.x & 63;
    int b = gid >> 9, co = gid & 511;
    const float4v* sp = (const float4v*)(s + b * CDIM);
    const float4v* rp = (const float4v*)(ws2 + co * CDIM);
    float acc = 0.f;
#pragma unroll
    for (int k = 0; k < 2; ++k) {
        float4v a = sp[lane * 2 + k], r = rp[lane * 2 + k];
        acc += a[0] * a[0] * r[0] + a[1] * a[1] * r[1]
             + a[2] * a[2] * r[2] + a[3] * a[3] * r[3];
    }
#pragma unroll
    for (int off = 32; off; off >>= 1) acc += __shfl_down(acc, off);
    const float wg = 0.014731391274719739f;          // 1/sqrt(4608)
    const float wg2 = 2.170138888888889e-4f;         // 1/4608
    if (lane == 0) osc[gid] = wg * rsqrtf(wg2 * acc + 1e-8f);
}

// wgt layout: [chunk16][ct4] regions of 36864 shorts.
// Within region: [t9][mf8][slot64][j8], slot = l4*16 + l15 (lane-linear),
// value = w[co = ct*128 + mf*16 + l15][ci = chunk*32 + l4*8 + j][t]
__global__ void k_wconv(const float* __restrict__ w, short* __restrict__ wgt) {
    int idx = blockIdx.x * 256 + threadIdx.x;  // 2359296
    int j = idx & 7;
    int slotg = idx >> 3;
    int region = slotg / 4608;         // chunk*4 + ct
    int a16 = slotg - region * 4608;
    int tm = a16 >> 6;                 // t*8 + mf
    int t = tm >> 3;
    int mf = tm & 7;
    int sl = a16 & 63;
    int l4 = sl >> 4;
    int l15 = sl & 15;
    int ct = region & 3;
    int c = region >> 2;
    int co = ct * 128 + mf * 16 + l15;
    int ci = c * 32 + l4 * 8 + j;
    wgt[idx] = f2bf(w[(co * CDIM + ci) * 9 + t]);
}

// xs layout: [b8][c16][grow64] rows of XROW=2112 shorts (66 px-cols x 32 ci):
// shorts at (px+1)*32 + sl*8 + j = bf16( x[b][ci=c*32+sl*8+j][grow][px] * s ),
// px-cols 0 and 65 are zero halos.
__global__ void k_xs(const float* __restrict__ x, const float* __restrict__ s,
                     short* __restrict__ xs) {
    const int bx = blockIdx.x;         // (b*16 + c)*64 + grow
    const int grow = bx & 63;
    const int t = bx >> 6;
    const int c = t & 15;
    const int b = t >> 4;
    const int px = threadIdx.x >> 2;   // 0..63
    const int sl = threadIdx.x & 3;    // ci 8-group
    const int ci0 = c * 32 + sl * 8;
    const float* xb = x + ((b * CDIM + ci0) * HW + grow) * HW + px;
    const float* sb = s + b * CDIM + ci0;
    short8 pk;
#pragma unroll
    for (int j = 0; j < 8; ++j)
        pk[j] = f2bf(xb[j * (HW * HW)] * sb[j]);
    short* rowp = xs + (size_t)bx * XROW;
    *(short8*)&rowp[(px + 1) * 32 + sl * 8] = pk;
    if (threadIdx.x < 8) {             // zero halo cols 0 and 65
        int col = (threadIdx.x >> 2) ? 65 : 0;
        int s2 = threadIdx.x & 3;
        short8 z = {};
        *(short8*)&rowp[col * 32 + s2 * 8] = z;
    }
}

// ---------------- main conv (v3: B from L2, W dbuf in LDS) ----------------
// grid 256 blocks x 512 threads. Block: (ct co-tile of 128, b, row-tile of 8).
// Wave = one output row: 128co x 64px.
__global__ __launch_bounds__(512, 1) void conv_main3(
    const short* __restrict__ xs, const short* __restrict__ zrow,
    const short* __restrict__ wgt, const float* __restrict__ osc,
    float* __restrict__ out) {

    __shared__ __align__(16) short w_lds[2][36864];   // 2 x 73728 B

    const int tid = threadIdx.x;
    const int lane = tid & 63;
    const int wr = tid >> 6;           // 0..7 = output row within tile
    const int l15 = lane & 15;
    const int l4 = lane >> 4;

    // b == xcd; the 4 ct-blocks of one (b,rt) group share the xs slice in L2.
    const int bx = blockIdx.x;
    const int xcd = bx & 7;
    const int t7 = bx >> 3;
    const int ct = t7 & 3;
    const int ghi = t7 >> 2;           // 0..7
    const int b = xcd;
    const int r0 = ghi * 8;

    const int voff = l15 * 32 + l4 * 8;   // lane-affine B offset (shorts)

    auto stage_w = [&](int c, int bufn) {   // 9 glls/wave
        const short* src = wgt + (c * 4 + ct) * 36864;
        short* dstb = &w_lds[bufn][0];
#pragma unroll
        for (int k = 0; k < 9; ++k) {
            int off = (k * 512 + wr * 64) * 8;
            async_ld16(src + off + lane * 8, dstb + off + lane * 8);
        }
    };

    float4v acc[8][4] = {};

#define TAPX(T)                                                                  \
    { const short* pd = ((T) < 3) ? p0 : (((T) < 6) ? p1 : p2);                  \
      const int dwp1 = (T) % 3;    /* dw+1: 0,1,2 */                             \
      short8 bfr[4];                                                             \
      _Pragma("unroll")                                                          \
      for (int nf = 0; nf < 4; ++nf)                                             \
          bfr[nf] = *(const short8*)(pd + voff + (nf * 16 + dwp1) * 32);         \
      _Pragma("unroll")                                                          \
      for (int mf = 0; mf < 8; ++mf) {                                           \
          short8 af = *(const short8*)&wb[(((T) * 8 + mf) * 64 + lane) * 8];     \
          _Pragma("unroll")                                                      \
          for (int nf = 0; nf < 4; ++nf)                                         \
              acc[mf][nf] = __builtin_amdgcn_mfma_f32_16x16x32_bf16(             \
                  af, bfr[nf], acc[mf][nf], 0, 0, 0);                            \
      } }

    // prologue: W(0) -> buf0, drain, publish
    stage_w(0, 0);
    hard_sync();

    const int gb = r0 + wr - 1;        // grow of dh=0 row for this wave
#pragma unroll 1
    for (int c = 0; c < NCHUNK; ++c) {
        const int buf = c & 1;
        const short* wb = &w_lds[buf][0];
        const short* xcb = xs + ((size_t)(b * 16 + c) * 64) * XROW;
        const short* p0 = ((unsigned)(gb + 0) < 64u) ? xcb + (size_t)(gb + 0) * XROW : zrow;
        const short* p1 = ((unsigned)(gb + 1) < 64u) ? xcb + (size_t)(gb + 1) * XROW : zrow;
        const short* p2 = ((unsigned)(gb + 2) < 64u) ? xcb + (size_t)(gb + 2) * XROW : zrow;

        TAPX(0)
        // issue next-chunk W glls after tap0 so tap1+'s B-load waits find them
        // already (or nearly) landed; they ride under taps 1..8 (~10k cyc).
        stage_w((c + 1 < NCHUNK) ? c + 1 : NCHUNK - 1, buf ^ 1);
        __builtin_amdgcn_s_setprio(1);
        TAPX(1) TAPX(2) TAPX(3) TAPX(4)
        TAPX(5) TAPX(6) TAPX(7) TAPX(8)
        __builtin_amdgcn_s_setprio(0);

        // drain own glls (long since landed) + B stragglers; publish W(c+1)
        asm volatile("s_waitcnt vmcnt(0)" ::: "memory");
        __builtin_amdgcn_sched_barrier(0);
        __builtin_amdgcn_s_barrier();
        __builtin_amdgcn_sched_barrier(0);
    }
#undef TAPX

    // epilogue: demodulate + store
    const int row_out = r0 + wr;
#pragma unroll
    for (int mf = 0; mf < 8; ++mf) {
        float4v ov = *(const float4v*)&osc[b * CDIM + ct * 128 + mf * 16 + l4 * 4];
#pragma unroll
        for (int j = 0; j < 4; ++j) {
            int co = ct * 128 + mf * 16 + l4 * 4 + j;
            float* po = out + ((b * CDIM + co) * HW + row_out) * HW;
#pragma unroll
            for (int nf = 0; nf < 4; ++nf)
                po[nf * 16 + l15] = acc[mf][nf][j] * ov[j];
        }
    }
}

// ---------------- fallback conv (round-4 proven, reg-staged x) ----------------
__global__ __launch_bounds__(512, 1) void conv_main_fb(
    const float* __restrict__ x, const float* __restrict__ s,
    const short* __restrict__ wgt, const float* __restrict__ osc,
    float* __restrict__ out) {

    __shared__ __align__(16) short w_lds[9 * 8 * 64 * 8];
    __shared__ __align__(16) short x_lds[2][10 * 66 * 32];

    const int tid = threadIdx.x;
    const int lane = tid & 63;
    const int wid = tid >> 6;
    const int l15 = lane & 15;
    const int l4 = lane >> 4;

    const int bx = blockIdx.x;
    const int xcd = bx & 7;
    const int t7 = bx >> 3;
    const int ct = t7 & 3;
    const int ghi = t7 >> 2;
    const int b = xcd;
    const int r0 = ghi * 8;

    const int cig = tid & 3;
    const int col = (tid >> 2) & 63;
    const int rowhalf = tid >> 8;

    for (int i = tid; i < 640; i += 512) {
        int bufi = i >= 320;
        int v = i - bufi * 320;
        int row = v >> 5;
        int w16 = v & 31;
        int colh = (w16 >= 16) ? 65 : 0;
        int q16 = w16 & 15;
        ((unsigned*)x_lds[bufi])[(row * 66 + colh) * 16 + q16] = 0u;
    }

    float rx[40];
    float4v sva, svb;

    auto stage_w = [&](int c) {
        const short* src = wgt + (c * 4 + ct) * 36864;
#pragma unroll
        for (int k = 0; k < 9; ++k) {
            int off = (k * 512 + wid * 64) * 8;
            async_ld16(src + off + lane * 8, w_lds + off);
        }
    };

    auto stage_x_load = [&](int c) {
        const float4v* sp = (const float4v*)&s[b * CDIM + c * 32 + cig * 8];
        sva = sp[0]; svb = sp[1];
#pragma unroll
        for (int i = 0; i < 5; ++i) {
            int row = 2 * i + rowhalf;
            int grow = r0 - 1 + row;
            bool ok = (grow >= 0) && (grow < HW);
            const float* base = x + ((b * CDIM + c * 32 + cig * 8) * HW + (ok ? grow : 0)) * HW + col;
#pragma unroll
            for (int j = 0; j < 8; ++j) {
                float v = base[j * (HW * HW)];
                rx[i * 8 + j] = ok ? v : 0.0f;
            }
        }
    };

    auto stage_x_write = [&](int buf) {
        int lcol = col + 1;
        int q = cig ^ ((lcol >> 1) & 3);
#pragma unroll
        for (int i = 0; i < 5; ++i) {
            int row = 2 * i + rowhalf;
            short8 pk;
#pragma unroll
            for (int j = 0; j < 8; ++j) {
                float sj = (j < 4) ? sva[j] : svb[j - 4];
                pk[j] = f2bf(rx[i * 8 + j] * sj);
            }
            *(short8*)&x_lds[buf][(row * 66 + lcol) * 32 + q * 8] = pk;
        }
    };

    float4v acc[8][4] = {};

    auto compute = [&](int buf) {
        const short* xb = x_lds[buf];
#pragma unroll
        for (int t = 0; t < 9; ++t) {
            int dh = t / 3 - 1;
            int dw = t % 3 - 1;
            int lrow = wid + dh + 1;
            short8 bfr[4];
#pragma unroll
            for (int nf = 0; nf < 4; ++nf) {
                int lcol = 1 + nf * 16 + l15 + dw;
                int xq = l4 ^ ((lcol >> 1) & 3);
                bfr[nf] = *(const short8*)&xb[(lrow * 66 + lcol) * 32 + xq * 8];
            }
#pragma unroll
            for (int mf = 0; mf < 8; ++mf) {
                short8 af = *(const short8*)&w_lds[((t * 8 + mf) * 64 + lane) * 8];
#pragma unroll
                for (int nf = 0; nf < 4; ++nf)
                    acc[mf][nf] = __builtin_amdgcn_mfma_f32_16x16x32_bf16(
                        af, bfr[nf], acc[mf][nf], 0, 0, 0);
            }
        }
    };

    stage_w(0);
    stage_x_load(0);
    stage_x_write(0);
    hard_sync();

    int cur = 0;
#pragma unroll 1
    for (int c = 0; c < NCHUNK; ++c) {
        if (c + 1 < NCHUNK) stage_x_load(c + 1);
        compute(cur);
        if (c + 1 < NCHUNK) {
            hard_sync();
            stage_w(c + 1);
            stage_x_write(cur ^ 1);
            hard_sync();
            cur ^= 1;
        }
    }

    const int row_out = r0 + wid;
#pragma unroll
    for (int mf = 0; mf < 8; ++mf) {
        float4v ov = *(const float4v*)&osc[b * CDIM + ct * 128 + mf * 16 + l4 * 4];
#pragma unroll
        for (int j = 0; j < 4; ++j) {
            int co = ct * 128 + mf * 16 + l4 * 4 + j;
            float* po = out + ((b * CDIM + co) * HW + row_out) * HW;
#pragma unroll
            for (int nf = 0; nf < 4; ++nf)
                po[nf * 16 + l15] = acc[mf][nf][j] * ov[j];
        }
    }
}

// ---------------- launcher ----------------

extern "C" void kernel_launch(void* const* d_in, const int* in_sizes, int n_in,
                              void* d_out, int out_size, void* d_ws, size_t ws_size,
                              hipStream_t stream) {
    const float* x     = (const float*)d_in[0];   // 8*512*64*64
    const float* style = (const float*)d_in[1];   // 8*512
    const float* w     = (const float*)d_in[2];   // 512*512*9
    const float* aw    = (const float*)d_in[3];   // 512*512
    const float* ab    = (const float*)d_in[4];   // 512
    float* out = (float*)d_out;

    char* wsb = (char*)d_ws;
    float* s_buf = (float*)(wsb);                 // 16384 B
    float* ws2   = (float*)(wsb + 16384);         // 1048576 B
    float* osc   = (float*)(wsb + 1064960);       // 16384 B
    short* wgt   = (short*)(wsb + 1081344);       // 4718592 B
    short* zrow  = (short*)(wsb + 5799936);       // 4224 B zero row (pad to 4352)
    short* xs    = (short*)(wsb + 5804288);       // 34603008 B
    const size_t need = 5804288ull + 34603008ull; // ~40.4 MB

    k_affine<<<1024, 256, 0, stream>>>(style, aw, ab, s_buf);
    k_ws2<<<1024, 256, 0, stream>>>(w, ws2);
    k_wconv<<<9216, 256, 0, stream>>>(w, wgt);
    k_oscale<<<1024, 256, 0, stream>>>(s_buf, ws2, osc);

    if (ws_size >= need) {
        hipMemsetAsync(zrow, 0, 4352, stream);
        k_xs<<<8192, 256, 0, stream>>>(x, s_buf, xs);
        conv_main3<<<256, 512, 0, stream>>>(xs, zrow, wgt, osc, out);
    } else {
        conv_main_fb<<<256, 512, 0, stream>>>(x, s_buf, wgt, osc, out);
    }
}